// Round 7
// baseline (346.007 us; speedup 1.0000x reference)
//
#include <hip/hip_runtime.h>
#include <math.h>

#define BB 16
#define NN 512
#define TT 32
#define CC 128
#define RR 32
#define DD 64

// fp32 Q/K handoff (module .bss; fully rewritten by k1 before k2f reads)
__device__ float g_Q[BB * NN * DD];
__device__ float g_K[BB * NN * DD];

// numpy npyv(AVX512) einsum contig-two dot emulation:
// 16-lane FMA single accumulator over ascending 16-blocks,
// then the _mm512_reduce_add_ps combine tree. All ops rounding-locked.
__device__ __forceinline__ float dot_np16(const float* __restrict__ a,
                                          const float* __restrict__ b, int n) {
    float lane[16];
#pragma unroll
    for (int l = 0; l < 16; ++l) lane[l] = 0.0f;
    for (int i = 0; i < n; i += 16) {
#pragma unroll
        for (int l = 0; l < 16; ++l)
            lane[l] = __fmaf_rn(a[i + l], b[i + l], lane[l]);
    }
    float m[8], p[4];
#pragma unroll
    for (int i = 0; i < 8; ++i) m[i] = __fadd_rn(lane[i], lane[i + 8]);
#pragma unroll
    for (int i = 0; i < 4; ++i) p[i] = __fadd_rn(m[i], m[i + 4]);
    float q0 = __fadd_rn(p[0], p[2]);
    float q1 = __fadd_rn(p[1], p[3]);
    return __fadd_rn(q0, q1);
}

// ------------- Kernel 1: per-(b,n) pipeline -> Q,K (fp32-faithful) -----------
__global__ __launch_bounds__(256) void k1(const float* __restrict__ x,
        const float* __restrict__ Ws, const float* __restrict__ Wphi,
        const float* __restrict__ b_phi, const float* __restrict__ Wmu,
        const float* __restrict__ b_mu, const float* __restrict__ WQ,
        const float* __restrict__ WK)
{
    __shared__ float Xs[TT][CC];
    __shared__ float Xh[TT][CC];
    __shared__ float zta[TT][RR];
    __shared__ float avg[CC];        // reused later as X_c
    __shared__ float wsh[CC];
    __shared__ float zca[RR];
    __shared__ float lg[TT];
    __shared__ float alpha[TT];

    const int tid = threadIdx.x;
    const int bn = blockIdx.x;
    const float* xb = x + (long long)bn * (TT * CC);

    for (int i = tid; i < TT * CC; i += 256) Xs[i >> 7][i & 127] = xb[i];
    __syncthreads();

    // avg = np.mean over t: numpy pairwise 8-accumulator pattern, /32 (exact)
    if (tid < CC) {
        float r[8];
#pragma unroll
        for (int j = 0; j < 8; ++j) r[j] = Xs[j][tid];
#pragma unroll
        for (int i = 8; i < 32; i += 8)
#pragma unroll
            for (int j = 0; j < 8; ++j) r[j] = __fadd_rn(r[j], Xs[i + j][tid]);
        float s = __fadd_rn(__fadd_rn(__fadd_rn(r[0], r[1]), __fadd_rn(r[2], r[3])),
                            __fadd_rn(__fadd_rn(r[4], r[5]), __fadd_rn(r[6], r[7])));
        avg[tid] = s / 32.0f;
    }
    __syncthreads();

    // z_ca = relu(einsum('c,rc->r', avg, Ws))
    if (tid < RR) zca[tid] = fmaxf(dot_np16(avg, Ws + tid * CC, CC), 0.0f);
    __syncthreads();

    // w = sigmoid(einsum('r,cr->c', zca, Wphi) + b_phi)
    if (tid < CC) {
        float t = __fadd_rn(dot_np16(zca, Wphi + tid * RR, RR), b_phi[tid]);
        wsh[tid] = 1.0f / (1.0f + expf(-t));
    }
    __syncthreads();

    // X_hat = X * w (elementwise fp32)
    for (int i = tid; i < TT * CC; i += 256) {
        int t = i >> 7, c = i & 127;
        Xh[t][c] = __fmul_rn(Xs[t][c], wsh[c]);
    }
    __syncthreads();

    // z_ta = relu(einsum('tc,rc->tr', X_hat, Ws))
    for (int i = tid; i < TT * RR; i += 256) {
        int t = i >> 5, r = i & 31;
        zta[t][r] = fmaxf(dot_np16(Xh[t], Ws + r * CC, CC), 0.0f);
    }
    __syncthreads();

    // logits
    if (tid < TT) lg[tid] = __fadd_rn(dot_np16(zta[tid], Wmu, RR), b_mu[0]);
    __syncthreads();

    // softmax over t (selection-insensitive to order; mimic np anyway)
    if (tid == 0) {
        float m = lg[0];
        for (int t = 1; t < TT; ++t) m = fmaxf(m, lg[t]);
        float e[TT];
        for (int t = 0; t < TT; ++t) e[t] = expf(__fsub_rn(lg[t], m));
        float r[8];
#pragma unroll
        for (int j = 0; j < 8; ++j) r[j] = e[j];
#pragma unroll
        for (int i = 8; i < 32; i += 8)
#pragma unroll
            for (int j = 0; j < 8; ++j) r[j] = __fadd_rn(r[j], e[i + j]);
        float s = __fadd_rn(__fadd_rn(__fadd_rn(r[0], r[1]), __fadd_rn(r[2], r[3])),
                            __fadd_rn(__fadd_rn(r[4], r[5]), __fadd_rn(r[6], r[7])));
        for (int t = 0; t < TT; ++t) alpha[t] = e[t] / s;
    }
    __syncthreads();

    // X_c = einsum('t,tc->c', alpha, X_hat): strided -> scalar sequential FMA
    if (tid < CC) {
        float s = 0.0f;
        for (int t = 0; t < TT; ++t) s = __fmaf_rn(alpha[t], Xh[t][tid], s);
        avg[tid] = s;   // reuse avg[] as X_c (its consumers are long done)
    }
    __syncthreads();

    // Q, K projections
    if (tid < 128) {
        int isK = tid >> 6, d = tid & 63;
        const float* Wr = (isK ? WK : WQ) + d * CC;
        float s = dot_np16(avg, Wr, CC);
        if (isK) g_K[bn * DD + d] = s;
        else     g_Q[bn * DD + d] = s;
    }
}

// ------------- Kernel 2: E rows (np-order fp32) + sigmoid-domain top-8 -------
__device__ __forceinline__ void cxf(float& a, float& b) {
    float mx = fmaxf(a, b), mn = fminf(a, b);
    a = mx; b = mn;
}

__global__ __launch_bounds__(256) void k2f(float* __restrict__ out)
{
    __shared__ float Qs[16][64];
    __shared__ float Kch[64][65];    // one 64-column chunk of the 512-row matrix

    const int tid = threadIdx.x;
    const int gid = blockIdx.x;
    const int dir = gid & 1;
    const int b   = (gid >> 1) & 15;
    const int grp = gid >> 5;                 // 0..31
    const int row_base = grp << 4;

    const float* Qrow = dir ? g_K : g_Q;      // backward: rows come from K
    const float* Mat  = dir ? g_Q : g_K;
    float* outp = out + (long long)dir * BB * NN * NN;

    for (int k = 0; k < 4; ++k) {
        int idx = tid + (k << 8);
        Qs[idx >> 6][idx & 63] =
            Qrow[(long long)(b * NN + row_base + (idx >> 6)) * DD + (idx & 63)];
    }

    const int l = tid & 63, w = tid >> 6, wrow = w << 2;
    float A[4][8];

#pragma unroll
    for (int j = 0; j < 8; ++j) {             // 8 column chunks of 64
        __syncthreads();                       // covers Qs on j==0, Kch reuse after
        for (int k = 0; k < 16; ++k) {
            int idx = tid + (k << 8);
            int row = idx >> 6, d = idx & 63;
            Kch[row][d] = Mat[(long long)(b * NN + (j << 6) + row) * DD + d];
        }
        __syncthreads();
#pragma unroll
        for (int r = 0; r < 4; ++r) {
            float e = dot_np16(Qs[wrow + r], Kch[l], DD);
            e = e / 8.0f;                      // scale = sqrt(64), exact
            A[r][j] = 1.0f / (1.0f + expf(-e));  // select in sigmoid domain
        }
    }

    const long long obase = (long long)(b * NN + row_base + wrow) * NN;

#pragma unroll
    for (int r = 0; r < 4; ++r) {
        float L[8];
#pragma unroll
        for (int j = 0; j < 8; ++j) L[j] = A[r][j];

        // Batcher odd-even merge sort, 8 elems, descending
        cxf(L[0],L[1]); cxf(L[2],L[3]); cxf(L[4],L[5]); cxf(L[6],L[7]);
        cxf(L[0],L[2]); cxf(L[1],L[3]); cxf(L[4],L[6]); cxf(L[5],L[7]);
        cxf(L[1],L[2]); cxf(L[5],L[6]);
        cxf(L[0],L[4]); cxf(L[1],L[5]); cxf(L[2],L[6]); cxf(L[3],L[7]);
        cxf(L[2],L[4]); cxf(L[3],L[5]);
        cxf(L[1],L[2]); cxf(L[3],L[4]); cxf(L[5],L[6]);

        // 64-lane butterfly merge: global top-8 of the row in every lane
#pragma unroll
        for (int mask = 1; mask < 64; mask <<= 1) {
            float Pr[8], M[8];
#pragma unroll
            for (int j = 0; j < 8; ++j) Pr[j] = __shfl_xor(L[j], mask, 64);
#pragma unroll
            for (int j = 0; j < 8; ++j) M[j] = fmaxf(L[j], Pr[7 - j]);
            cxf(M[0],M[4]); cxf(M[1],M[5]); cxf(M[2],M[6]); cxf(M[3],M[7]);
            cxf(M[0],M[2]); cxf(M[1],M[3]); cxf(M[4],M[6]); cxf(M[5],M[7]);
            cxf(M[0],M[1]); cxf(M[2],M[3]); cxf(M[4],M[5]); cxf(M[6],M[7]);
#pragma unroll
            for (int j = 0; j < 8; ++j) L[j] = M[j];
        }
        const float kth = L[7];

        float* orow = outp + obase + (long long)r * NN;
#pragma unroll
        for (int j = 0; j < 8; ++j)
            orow[(j << 6) + l] = (A[r][j] >= kth) ? A[r][j] : 0.0f;
    }
}

extern "C" void kernel_launch(void* const* d_in, const int* in_sizes, int n_in,
                              void* d_out, int out_size, void* d_ws, size_t ws_size,
                              hipStream_t stream) {
    const float* x     = (const float*)d_in[0];
    const float* Ws    = (const float*)d_in[1];
    const float* Wphi  = (const float*)d_in[2];
    const float* b_phi = (const float*)d_in[3];
    const float* Wmu   = (const float*)d_in[4];
    const float* b_mu  = (const float*)d_in[5];
    const float* WQ    = (const float*)d_in[6];
    const float* WK    = (const float*)d_in[7];
    float* out = (float*)d_out;

    hipLaunchKernelGGL(k1, dim3(8192), dim3(256), 0, stream,
                       x, Ws, Wphi, b_phi, Wmu, b_mu, WQ, WK);
    hipLaunchKernelGGL(k2f, dim3(1024), dim3(256), 0, stream, out);
}